// Round 11
// baseline (66.766 us; speedup 1.0000x reference)
//
#include <hip/hip_runtime.h>
#include <hip/hip_bf16.h>

#define TT 1024
#define AA 16
#define S2 6.25f      // 1/(0.4^2)
#define EPSV 1e-6f
#define CHUNK 63      // u's per block (63 so the 64-lane slice covers all ws needs)
#define NCY 17        // ceil(1024/63)

typedef float f4 __attribute__((ext_vector_type(4)));

// One fused kernel. Block (kt, cy): k-rows [kt*32, kt*32+32) x u-chunk
// [U0, U0+NU), U0 = cy*63. Coefficient of pg[k,u,j,c] in out[2k+c]:
//   coef[u] = ws[u+1]-2*ws[u]  for u >= k-1 (coef[1023] = 0)
//   ws[k-1]                    for u == k-2
//   0 otherwise; k = 0 excluded.
// Phase A computes ws slices t in [U0, U0+63] from ado inputs (L2-resident,
// ~260 KB redundant reads/block); phase B streams the pg tile. No grid sync.
__global__ __launch_bounds__(256) void fused_kernel(const float* __restrict__ ado,
                                                    const float* __restrict__ ado_wo,
                                                    const float* __restrict__ pg,
                                                    float* __restrict__ out) {
    const int kt = blockIdx.x;
    const int cy = blockIdx.y;
    const int U0 = cy * CHUNK;
    const int k0 = kt * 32;
    if (k0 > U0 + 64) return;          // no row in this tile touches this chunk

    const int tid  = threadIdx.x;
    const int wave = tid >> 6;
    const int lane = tid & 63;

    __shared__ float lds_w[4][64][17];          // per-wave w partials [s][j]
    __shared__ float lds_sx[64][17], lds_sy[64][17];
    __shared__ float ws_lds[64][32];            // ws slice [s][j*2+c]
    __shared__ float red[4][64];

    // ---------------- phase A: ws slice for t = U0 + s, s in [0,64) ----------
    {
        const float2* A2 = (const float2*)ado;
        const float2* B2 = (const float2*)ado_wo;
        const int t  = U0 + lane;
        const int tl = (t < TT - 1) ? t : TT - 1;        // clamp (cy=16 tail)
        const int tm = (U0 > 0) ? U0 - 1 : 0;            // lane 0's t-1
        const int tp = (U0 + 64 < TT) ? U0 + 64 : TT-1;  // lane 63's t+1
        const float msk = (t > 0 && t < TT - 1) ? S2 : 0.f;

        float wacc[16];
        #pragma unroll
        for (int i = 0; i < 16; ++i) wacc[i] = 0.f;

        #pragma unroll
        for (int ro = 0; ro < 4; ++ro) {                 // s-target j = wave*4+ro
            float sxl = 0.f, syl = 0.f;
            #pragma unroll
            for (int ri = 0; ri < 16; ++ri) {            // w-target j = ri
                const int r = wave * 64 + ro * 16 + ri;  // flat row a*16+j
                const float2* Ar = A2 + r * TT;
                const float2* Br = B2 + r * TT;
                float2 av = Ar[tl], bv = Br[tl];
                float dx = av.x - bv.x, dy = av.y - bv.y;
                float2 am = Ar[tm], bm = Br[tm];         // uniform (1 line)
                float2 ap = Ar[tp], bp = Br[tp];         // uniform (1 line)
                float dmx = __shfl_up(dx, 1, 64);
                float dmy = __shfl_up(dy, 1, 64);
                if (lane == 0)  { dmx = am.x - bm.x; dmy = am.y - bm.y; }
                float dpx = __shfl_down(dx, 1, 64);
                float dpy = __shfl_down(dy, 1, 64);
                if (lane == 63) { dpx = ap.x - bp.x; dpy = ap.y - bp.y; }
                float ddx = (dmx - 2.f * dx + dpx) * msk;
                float ddy = (dmy - 2.f * dy + dpy) * msk;
                float n = sqrtf(ddx * ddx + ddy * ddy);
                wacc[ri] += (n < EPSV) ? 0.f : 1.f / n;
                sxl += ddx; syl += ddy;
            }
            lds_sx[lane][wave * 4 + ro] = sxl;           // j-disjoint per wave
            lds_sy[lane][wave * 4 + ro] = syl;
        }
        #pragma unroll
        for (int i = 0; i < 16; ++i) lds_w[wave][lane][i] = wacc[i];
    }
    __syncthreads();
    // combine: ws[s][j][c] = W[j,s] * S[j,s,c]
    #pragma unroll
    for (int it = 0; it < 4; ++it) {
        int item = tid + it * 256;        // 1024 = 64 s x 16 j
        int s = item >> 4, j = item & 15;
        float W = lds_w[0][s][j] + lds_w[1][s][j] + lds_w[2][s][j] + lds_w[3][s][j];
        ws_lds[s][2 * j]     = W * lds_sx[s][j];
        ws_lds[s][2 * j + 1] = W * lds_sy[s][j];
    }
    __syncthreads();

    // ---------------- phase B: stream pg tile ----------------
    const f4* __restrict__ pg4 = (const f4*)pg;
    const int NU = (TT - U0 < CHUNK) ? (TT - U0) : CHUNK;
    const int NQ = NU * 8;                        // f4 per row in this chunk
    const bool fast = (k0 + 31 <= U0 + 1);        // every row fully unmasked
    const f4 zero4 = {0.f, 0.f, 0.f, 0.f};

    #pragma unroll 1
    for (int rb = 0; rb < 4; ++rb) {
        const int kb = k0 + rb * 8;
        float axr[8], ayr[8];
        #pragma unroll
        for (int r = 0; r < 8; ++r) { axr[r] = 0.f; ayr[r] = 0.f; }

        #pragma unroll
        for (int i = 0; i < 2; ++i) {
            const int ql = tid + i * 256;
            if (ql < NQ) {
                const int s  = ql >> 3;          // <= 62
                const int jc = (ql & 7) * 4;
                const int u  = U0 + s;
                f4 wc = *(const f4*)&ws_lds[s][jc];
                f4 wp = *(const f4*)&ws_lds[s + 1][jc];
                f4 c  = wp - 2.f * wc;
                if (u >= TT - 1) c = zero4;      // coef[1023] = 0
                const int qg = U0 * 8 + ql;      // global f4 index in row
                if (fast) {
                    #pragma unroll
                    for (int r = 0; r < 8; ++r) {
                        f4 p = pg4[(kb + r) * 8192 + qg];
                        axr[r] += p.x * c.x + p.z * c.z;
                        ayr[r] += p.y * c.y + p.w * c.w;
                    }
                } else {
                    #pragma unroll
                    for (int r = 0; r < 8; ++r) {
                        const int k = kb + r;
                        if (k > U0 + 64) continue;          // row void
                        f4 p = pg4[k * 8192 + qg];
                        f4 eff;
                        if (u >= k - 1)      eff = c;
                        else if (u == k - 2) eff = *(const f4*)&ws_lds[k - 1 - U0][jc];
                        else                 eff = zero4;
                        axr[r] += p.x * eff.x + p.z * eff.z;
                        ayr[r] += p.y * eff.y + p.w * eff.w;
                    }
                }
            }
        }

        #pragma unroll
        for (int off = 32; off > 0; off >>= 1) {
            #pragma unroll
            for (int r = 0; r < 8; ++r) {
                axr[r] += __shfl_down(axr[r], off, 64);
                ayr[r] += __shfl_down(ayr[r], off, 64);
            }
        }
        if (lane == 0) {
            #pragma unroll
            for (int r = 0; r < 8; ++r) {
                red[wave][rb * 16 + 2 * r]     = axr[r];
                red[wave][rb * 16 + 2 * r + 1] = ayr[r];
            }
        }
    }
    __syncthreads();
    if (tid < 64) {
        float v = red[0][tid] + red[1][tid] + red[2][tid] + red[3][tid];
        const int rb = tid >> 4, r = (tid >> 1) & 7, comp = tid & 1;
        const int k = k0 + rb * 8 + r;
        if (k >= 1) atomicAdd(&out[2 * k + comp], v);
    }
}

extern "C" void kernel_launch(void* const* d_in, const int* in_sizes, int n_in,
                              void* d_out, int out_size, void* d_ws, size_t ws_size,
                              hipStream_t stream) {
    const float* ado    = (const float*)d_in[0];
    const float* ado_wo = (const float*)d_in[1];
    const float* pg     = (const float*)d_in[2];
    float* out = (float*)d_out;

    hipMemsetAsync(out, 0, (size_t)out_size * sizeof(float), stream);
    fused_kernel<<<dim3(32, NCY), 256, 0, stream>>>(ado, ado_wo, pg, out);
}